// Round 1
// 1489.035 us; speedup vs baseline: 1.1143x; 1.1143x over previous
//
#include <hip/hip_runtime.h>
#include <math.h>

#define BB 4096
#define GG 256
#define DD 32
#define CE 8192

__device__ __forceinline__ float softplusf_(float x) {
    return fmaxf(x, 0.0f) + log1pf(expf(-fabsf(x)));
}
__device__ __forceinline__ float sigmoidf_(float x) {
    return 1.0f / (1.0f + expf(-x));
}

// Unified table: tall[((ty<<8)+g)*640 + j]
//   j   0..127 : power   W1 partial (sum_d emb[ty][d]*pw1[(g*32+d)][j])
//   j 128..255 : delay   W1 partial
//   j 256..383 : stability W1 partial
//   j 384..639 : correctness W1 partial (256-wide)
// As float4 rows of 160: thread t<160 reads float4 index ((gt<<8)+g)*160 + t.
__global__ void build_tables(const float* __restrict__ emb,
                             const float* __restrict__ pw1,
                             const float* __restrict__ dw1,
                             const float* __restrict__ nw1,
                             const float* __restrict__ cw1,
                             float* __restrict__ tall) {
    const int g  = blockIdx.x;   // 0..255
    const int ty = blockIdx.y;   // 0..3
    const int h  = threadIdx.x;  // 0..255
    __shared__ float se[DD];
    if (h < DD) se[h] = emb[ty * DD + h];
    __syncthreads();
    float ap = 0.f, ad = 0.f, an = 0.f, ac = 0.f;
    const int rbase = g * DD;
#pragma unroll
    for (int d = 0; d < DD; ++d) {
        const float e = se[d];
        const int r = rbase + d;
        if (h < 128) {
            ap = fmaf(e, pw1[r * 128 + h], ap);
            ad = fmaf(e, dw1[r * 128 + h], ad);
            an = fmaf(e, nw1[r * 128 + h], an);
        }
        ac = fmaf(e, cw1[r * 256 + h], ac);
    }
    float* dst = tall + (size_t)(((ty << 8) + g)) * 640;
    if (h < 128) {
        dst[h]       = ap;
        dst[128 + h] = ad;
        dst[256 + h] = an;
    }
    dst[384 + h] = ac;
}

__global__ __launch_bounds__(256) void circuit_main(
    const int*   __restrict__ gate_types,
    const float* __restrict__ connections,
    const float* __restrict__ inputs,
    const float* __restrict__ outputs,
    const float* __restrict__ pb1, const float* __restrict__ pw2, const float* __restrict__ pb2,
    const float* __restrict__ db1, const float* __restrict__ dw2, const float* __restrict__ db2,
    const float* __restrict__ nb1, const float* __restrict__ nw2, const float* __restrict__ nb2,
    const float* __restrict__ cw1, const float* __restrict__ cb1,
    const float* __restrict__ cw2, const float* __restrict__ cb2,
    const float* __restrict__ cw3, const float* __restrict__ cb3,
    const float* __restrict__ tall,
    float* __restrict__ out)
{
    const int b = blockIdx.x;
    const int t = threadIdx.x;

    __shared__ int   s_gt[GG];     // packed ((gt<<8)+g)*160 (float4 row base)
    __shared__ int   s_cnt[4];
    __shared__ float s_io[12];
    __shared__ float s_red[96];
    __shared__ float s_hc[256];
    __shared__ float s_wred[4];
    __shared__ float s_logit[3];
    __shared__ float s_cred[2];

    if (t < 4) s_cnt[t] = 0;
    __syncthreads();
    {
        const int gt = gate_types[b * GG + t];
        atomicAdd(&s_cnt[gt], 1);
        s_gt[t] = ((gt << 8) + t) * 160;   // precomputed float4 base for tall gather
        if (t < 8)       s_io[t] = inputs[b * 8 + t];
        else if (t < 12) s_io[t] = outputs[b * 4 + (t - 8)];
    }
    __syncthreads();

    const float4* tall4 = (const float4*)tall;
    const float4* connb = (const float4*)(connections + (size_t)b * (GG * GG));
    const bool active = (t < 160);

    float ax = 0.f, ay = 0.f, az = 0.f, aw = 0.f;
    float cs = 0.f;

    // chunks of 16 g: 4 independent HBM conn loads issued first (latency hides
    // under the 16 L2 table gathers), then gather burst, then conn accumulate.
    for (int gc = 0; gc < GG; gc += 16) {
        float4 c0 = connb[((gc >> 2) + 0) * 256 + t];
        float4 c1 = connb[((gc >> 2) + 1) * 256 + t];
        float4 c2 = connb[((gc >> 2) + 2) * 256 + t];
        float4 c3 = connb[((gc >> 2) + 3) * 256 + t];
        if (active) {
#pragma unroll
            for (int gg = 0; gg < 16; ++gg) {
                const float4 v = tall4[s_gt[gc + gg] + t];
                ax += v.x; ay += v.y; az += v.z; aw += v.w;
            }
        }
        cs += (c0.x + c0.y) + (c0.z + c0.w);
        cs += (c1.x + c1.y) + (c1.z + c1.w);
        cs += (c2.x + c2.y) + (c2.z + c2.w);
        cs += (c3.x + c3.y) + (c3.z + c3.w);
    }

    // connection-count reduction (all 256 threads)
#pragma unroll
    for (int o = 32; o > 0; o >>= 1) cs += __shfl_down(cs, o, 64);
    if ((t & 63) == 0) s_wred[t >> 6] = cs;

    if (t < 96) {
        // power/delay/stability head: relu(h+b1) . w2 partials
        const int hb = (t & 31) * 4;
        const float* b1 = (t < 32) ? pb1 : (t < 64) ? db1 : nb1;
        const float* w2 = (t < 32) ? pw2 : (t < 64) ? dw2 : nw2;
        const float h0 = fmaxf(ax + b1[hb + 0], 0.f);
        const float h1 = fmaxf(ay + b1[hb + 1], 0.f);
        const float h2 = fmaxf(az + b1[hb + 2], 0.f);
        const float h3 = fmaxf(aw + b1[hb + 3], 0.f);
        s_red[t] = h0 * w2[hb + 0] + h1 * w2[hb + 1] + h2 * w2[hb + 2] + h3 * w2[hb + 3];
    } else if (t < 160) {
        // correctness hidden-1: add input/output rows of cw1, bias, relu -> LDS
        const int h = (t - 96) * 4;
#pragma unroll
        for (int j = 0; j < 12; ++j) {
            const float s = s_io[j];
            const float4 w = *(const float4*)&cw1[(size_t)(CE + j) * 256 + h];
            ax = fmaf(s, w.x, ax); ay = fmaf(s, w.y, ay);
            az = fmaf(s, w.z, az); aw = fmaf(s, w.w, aw);
        }
        s_hc[h + 0] = fmaxf(ax + cb1[h + 0], 0.f);
        s_hc[h + 1] = fmaxf(ay + cb1[h + 1], 0.f);
        s_hc[h + 2] = fmaxf(az + cb1[h + 2], 0.f);
        s_hc[h + 3] = fmaxf(aw + cb1[h + 3], 0.f);
    }
    __syncthreads();

    // correctness layer 2 (256->128) + layer 3 dot, threads 0..127
    if (t < 128) {
        float a = 0.f;
#pragma unroll 8
        for (int h = 0; h < 256; ++h) a = fmaf(s_hc[h], cw2[h * 128 + t], a);
        a = fmaxf(a + cb2[t], 0.f) * cw3[t];
#pragma unroll
        for (int o = 32; o > 0; o >>= 1) a += __shfl_down(a, o, 64);
        if ((t & 63) == 0) s_cred[t >> 6] = a;
    }
    // head logit finalization on otherwise-idle wave 2 threads
    if (t == 128) { float s = 0.f; for (int i = 0;  i < 32; ++i) s += s_red[i];      s_logit[0] = s + pb2[0]; }
    if (t == 129) { float s = 0.f; for (int i = 32; i < 64; ++i) s += s_red[i];      s_logit[1] = s + db2[0]; }
    if (t == 130) { float s = 0.f; for (int i = 64; i < 96; ++i) s += s_red[i];      s_logit[2] = s + nb2[0]; }
    __syncthreads();

    if (t == 0) {
        const float num_conn = s_wred[0] + s_wred[1] + s_wred[2] + s_wred[3];
        const float lp = s_logit[0], ld = s_logit[1], ln = s_logit[2];
        const float lc = s_cred[0] + s_cred[1] + cb3[0];

        const float energy = softplusf_(lp) + 0.05f * num_conn;  // 0.5 * 0.1

        float gate_ent = 0.f;
#pragma unroll
        for (int k = 0; k < 4; ++k) {
            const float c = (float)s_cnt[k];
            if (c > 0.f) {
                const float p = c * (1.0f / 256.0f);
                gate_ent -= p * log2f(p);
            }
        }
        const float dens = num_conn * (1.0f / 65536.0f);
        float conn_ent = 0.f;
        if (dens > 0.f && dens < 1.f) {
            const float dsf = fminf(fmaxf(dens, 1e-12f), 1.f - 1e-12f);
            conn_ent = -dsf * log2f(dsf) - (1.f - dsf) * log2f(1.f - dsf);
        }

        out[b]           = energy;
        out[BB + b]      = gate_ent + conn_ent;
        out[2 * BB + b]  = sigmoidf_(ln) * 0.36787944117144233f;  // exp(-1)
        out[3 * BB + b]  = sigmoidf_(lc);
        out[4 * BB + b]  = softplusf_(ld);
    }
}

extern "C" void kernel_launch(void* const* d_in, const int* in_sizes, int n_in,
                              void* d_out, int out_size, void* d_ws, size_t ws_size,
                              hipStream_t stream) {
    const int*   gate_types  = (const int*)  d_in[0];
    const float* connections = (const float*)d_in[1];
    const float* inputs      = (const float*)d_in[2];
    const float* outputs     = (const float*)d_in[3];
    const float* emb         = (const float*)d_in[4];
    const float* pw1 = (const float*)d_in[5];
    const float* pb1 = (const float*)d_in[6];
    const float* pw2 = (const float*)d_in[7];
    const float* pb2 = (const float*)d_in[8];
    const float* dw1 = (const float*)d_in[9];
    const float* db1 = (const float*)d_in[10];
    const float* dw2 = (const float*)d_in[11];
    const float* db2 = (const float*)d_in[12];
    const float* nw1 = (const float*)d_in[13];
    const float* nb1 = (const float*)d_in[14];
    const float* nw2 = (const float*)d_in[15];
    const float* nb2 = (const float*)d_in[16];
    const float* cw1 = (const float*)d_in[17];
    const float* cb1 = (const float*)d_in[18];
    const float* cw2 = (const float*)d_in[19];
    const float* cb2 = (const float*)d_in[20];
    const float* cw3 = (const float*)d_in[21];
    const float* cb3 = (const float*)d_in[22];

    float* tall = (float*)d_ws;   // 4*256*640 floats = 2.62 MB

    build_tables<<<dim3(256, 4), 256, 0, stream>>>(emb, pw1, dw1, nw1, cw1, tall);

    circuit_main<<<BB, 256, 0, stream>>>(
        gate_types, connections, inputs, outputs,
        pb1, pw2, pb2, db1, dw2, db2, nb1, nw2, nb2,
        cw1, cb1, cw2, cb2, cw3, cb3,
        tall,
        (float*)d_out);
}